// Round 3
// baseline (660.478 us; speedup 1.0000x reference)
//
#include <hip/hip_runtime.h>
#include <hip/hip_bf16.h>

#define EMB   1024
#define HEADS 16
#define HDIM  64
#define BB    4
#define SS    2048
#define MROWS (BB*SS)   // 8192

typedef __bf16 bf16_t;
typedef __bf16 bf16x8 __attribute__((ext_vector_type(8)));
typedef float  f32x4  __attribute__((ext_vector_type(4)));

// load 8 contiguous elements as bf16x8, converting if source is fp32
__device__ __forceinline__ bf16x8 load8(const float* p) {
  const float4 u = *(const float4*)p;
  const float4 v = *(const float4*)(p + 4);
  bf16x8 r;
  r[0] = (bf16_t)u.x; r[1] = (bf16_t)u.y; r[2] = (bf16_t)u.z; r[3] = (bf16_t)u.w;
  r[4] = (bf16_t)v.x; r[5] = (bf16_t)v.y; r[6] = (bf16_t)v.z; r[7] = (bf16_t)v.w;
  return r;
}
__device__ __forceinline__ bf16x8 load8(const bf16_t* p) {
  return *(const bf16x8*)p;
}
__device__ __forceinline__ void store_out(float* p, float v)  { *p = v; }
__device__ __forceinline__ void store_out(bf16_t* p, float v) { *p = (bf16_t)v; }

// ---------------------------------------------------------------------------
// C[M,N] = A[M,K] @ W[N,K]^T   (fp32 or bf16 in, fp32 accum, fp32 or bf16 out)
// 128x128 tile, BK=32, synchronous vector staging with on-the-fly bf16
// conversion, 16x16x32 bf16 MFMA.
// ---------------------------------------------------------------------------
template <typename TA, typename TW, typename TC>
__launch_bounds__(256)
__global__ void gemm_bt(const TA* __restrict__ A,
                        const TW* __restrict__ W,
                        TC* __restrict__ C,
                        int M, int N, int K) {
  __shared__ __align__(16) bf16_t As[128*32];
  __shared__ __align__(16) bf16_t Bs[128*32];
  const int tid  = threadIdx.x;
  const int wave = tid >> 6, lane = tid & 63;
  const int quad = lane >> 4, l16 = lane & 15;
  const int wm = wave >> 1, wn = wave & 1;
  const int bm0 = blockIdx.y * 128, bn0 = blockIdx.x * 128;

  f32x4 acc[4][4] = {};

  for (int k0 = 0; k0 < K; k0 += 32) {
    // stage A/B 128x32 tiles: 2 chunks of 8 elems per thread per matrix
#pragma unroll
    for (int c = 0; c < 2; ++c) {
      const int F   = (tid + c*256) * 8;       // flat elem idx in 128x32 tile
      const int row = F >> 5, col = F & 31;
      const bf16x8 av = load8(&A[(size_t)(bm0 + row)*K + (k0 + col)]);
      const bf16x8 bv = load8(&W[(size_t)(bn0 + row)*K + (k0 + col)]);
      *(bf16x8*)&As[F] = av;
      *(bf16x8*)&Bs[F] = bv;
    }
    __syncthreads();

    bf16x8 a[4], b[4];
#pragma unroll
    for (int t = 0; t < 4; ++t) {
      a[t] = *(const bf16x8*)&As[(wm*64 + t*16 + l16)*32 + quad*8];
      b[t] = *(const bf16x8*)&Bs[(wn*64 + t*16 + l16)*32 + quad*8];
    }
#pragma unroll
    for (int mt = 0; mt < 4; ++mt)
#pragma unroll
      for (int nt = 0; nt < 4; ++nt)
        acc[mt][nt] = __builtin_amdgcn_mfma_f32_16x16x32_bf16(a[mt], b[nt], acc[mt][nt], 0, 0, 0);
    __syncthreads();
  }

  // epilogue: C/D layout col=lane&15, row=quad*4+reg
#pragma unroll
  for (int mt = 0; mt < 4; ++mt) {
    const int row = bm0 + wm*64 + mt*16 + quad*4;
#pragma unroll
    for (int nt = 0; nt < 4; ++nt) {
      const int col = bn0 + wn*64 + nt*16 + l16;
#pragma unroll
      for (int r = 0; r < 4; ++r)
        store_out(&C[(size_t)(row + r)*N + col], acc[mt][nt][r]);
    }
  }
}

// ---------------------------------------------------------------------------
// Flash attention: block = (b, h, 64 Q-rows); 4 waves x 16 Q-rows each.
// K/V tiles of 64 keys staged in LDS (V transposed), online softmax,
// P goes C-layout -> LDS -> A-layout for PV.
// Qp and Cx may alias (each block reads only its own disjoint rows x
// head-cols slice into registers before writing the identical slice).
// ---------------------------------------------------------------------------
#define KPAD 72   // pad rows 64->72 elems (144B): 16B-aligned, spreads banks

__launch_bounds__(256)
__global__ void attn(const bf16_t* Qp, const bf16_t* __restrict__ Kp,
                     const bf16_t* __restrict__ Vp, bf16_t* Cx) {
  __shared__ __align__(16) bf16_t Ks[64*KPAD];     // [t][d]
  __shared__ __align__(16) bf16_t Vs[64*KPAD];     // [d][t] (transposed)
  __shared__ __align__(16) bf16_t Ps[4][16*KPAD];  // per-wave P [q][t]

  const int tid  = threadIdx.x;
  const int wave = tid >> 6, lane = tid & 63;
  const int quad = lane >> 4, l16 = lane & 15;
  const int b = blockIdx.z, h = blockIdx.y;
  const int q0 = blockIdx.x * 64;

  // Q fragments (A-operand): lane holds Q[m=l16][k=quad*8+j], 2 K-steps over D=64
  const size_t qoff = (size_t)(b*SS + q0 + wave*16 + l16)*EMB + h*HDIM;
  const bf16x8 qf0 = *(const bf16x8*)&Qp[qoff + quad*8];
  const bf16x8 qf1 = *(const bf16x8*)&Qp[qoff + 32 + quad*8];

  f32x4 o[4] = {};
  float mrun[4], lrun[4];
#pragma unroll
  for (int r = 0; r < 4; ++r) { mrun[r] = -__builtin_inff(); lrun[r] = 0.f; }

  const float sscale = 0.125f * 1.44269504f;  // 1/sqrt(64) * log2(e)

  for (int t0 = 0; t0 < SS; t0 += 64) {
    // stage K (natural) and V (transposed): 512 chunks of 8 bf16, 2 per thread
#pragma unroll
    for (int c = 0; c < 2; ++c) {
      const int ci = tid + c*256;
      const int r = ci >> 3, dcol = (ci & 7)*8;
      const size_t goff = (size_t)(b*SS + t0 + r)*EMB + h*HDIM + dcol;
      *(bf16x8*)&Ks[r*KPAD + dcol] = *(const bf16x8*)&Kp[goff];
      const bf16x8 vv = *(const bf16x8*)&Vp[goff];
#pragma unroll
      for (int j = 0; j < 8; ++j) Vs[(dcol + j)*KPAD + r] = vv[j];
    }
    __syncthreads();

    // S = Q K^T : 4 col-blocks of 16 keys, 2 K-steps each
    f32x4 s[4] = {};
#pragma unroll
    for (int cb = 0; cb < 4; ++cb) {
      const bf16x8 kf0 = *(const bf16x8*)&Ks[(cb*16 + l16)*KPAD + quad*8];
      const bf16x8 kf1 = *(const bf16x8*)&Ks[(cb*16 + l16)*KPAD + 32 + quad*8];
      s[cb] = __builtin_amdgcn_mfma_f32_16x16x32_bf16(qf0, kf0, s[cb], 0, 0, 0);
      s[cb] = __builtin_amdgcn_mfma_f32_16x16x32_bf16(qf1, kf1, s[cb], 0, 0, 0);
    }

    // online softmax per q-row (row = quad*4 + r); exp2 domain
#pragma unroll
    for (int r = 0; r < 4; ++r) {
      float mt = fmaxf(fmaxf(s[0][r], s[1][r]), fmaxf(s[2][r], s[3][r])) * sscale;
#pragma unroll
      for (int msk = 1; msk < 16; msk <<= 1)
        mt = fmaxf(mt, __shfl_xor(mt, msk, 64));
      const float mnew  = fmaxf(mrun[r], mt);
      const float alpha = exp2f(mrun[r] - mnew);
      mrun[r] = mnew;
      float p[4], rs = 0.f;
#pragma unroll
      for (int cb = 0; cb < 4; ++cb) {
        p[cb] = exp2f(s[cb][r]*sscale - mnew);
        rs += p[cb];
      }
#pragma unroll
      for (int msk = 1; msk < 16; msk <<= 1)
        rs += __shfl_xor(rs, msk, 64);
      lrun[r] = lrun[r]*alpha + rs;
#pragma unroll
      for (int nb = 0; nb < 4; ++nb) o[nb][r] *= alpha;
#pragma unroll
      for (int cb = 0; cb < 4; ++cb)
        Ps[wave][(quad*4 + r)*KPAD + cb*16 + l16] = (bf16_t)p[cb];
    }
    __syncthreads();

    // O += P V : P as A-operand from LDS, V^T as B-operand
#pragma unroll
    for (int ks = 0; ks < 2; ++ks) {
      const bf16x8 pf = *(const bf16x8*)&Ps[wave][l16*KPAD + ks*32 + quad*8];
#pragma unroll
      for (int nb = 0; nb < 4; ++nb) {
        const bf16x8 vf = *(const bf16x8*)&Vs[(nb*16 + l16)*KPAD + ks*32 + quad*8];
        o[nb] = __builtin_amdgcn_mfma_f32_16x16x32_bf16(pf, vf, o[nb], 0, 0, 0);
      }
    }
    __syncthreads();
  }

  // normalize + write ctx in [B,S,H*D] layout (= reshape in reference)
#pragma unroll
  for (int r = 0; r < 4; ++r) {
    const float inv = 1.0f / lrun[r];
    const size_t row = (size_t)(b*SS + q0 + wave*16 + quad*4 + r)*EMB + h*HDIM;
#pragma unroll
    for (int nb = 0; nb < 4; ++nb)
      Cx[row + nb*16 + l16] = (bf16_t)(o[nb][r]*inv);
  }
}

// ---------------------------------------------------------------------------
extern "C" void kernel_launch(void* const* d_in, const int* in_sizes, int n_in,
                              void* d_out, int out_size, void* d_ws, size_t ws_size,
                              hipStream_t stream) {
  (void)in_sizes; (void)n_in; (void)out_size; (void)ws_size;
  // Reference dtypes are float32 throughout -> inputs/output are fp32.
  const float* query = (const float*)d_in[0];
  const float* key   = (const float*)d_in[1];
  const float* value = (const float*)d_in[2];
  const float* Wq    = (const float*)d_in[3];
  const float* Wk    = (const float*)d_in[4];
  const float* Wv    = (const float*)d_in[5];
  const float* Wo    = (const float*)d_in[6];

  // bf16 intermediates. Qp | Kp in d_ws (32 MB). Vp lives in the first 16 MB
  // of d_out (32 MB fp32 buffer; dead before the final gemm overwrites it).
  // Cx aliases Qp (disjoint per-block slices, read-before-write per block).
  bf16_t* Qp = (bf16_t*)d_ws;
  bf16_t* Kp = Qp + (size_t)MROWS*EMB;
  bf16_t* Vp = (bf16_t*)d_out;
  bf16_t* Cx = Qp;
  float*  out = (float*)d_out;

  const dim3 gg(EMB/128, MROWS/128);  // (8, 64) = 512 blocks
  gemm_bt<float, float, bf16_t><<<gg, 256, 0, stream>>>(query, Wq, Qp, MROWS, EMB, EMB);
  gemm_bt<float, float, bf16_t><<<gg, 256, 0, stream>>>(key,   Wk, Kp, MROWS, EMB, EMB);
  gemm_bt<float, float, bf16_t><<<gg, 256, 0, stream>>>(value, Wv, Vp, MROWS, EMB, EMB);
  attn<<<dim3(SS/64, HEADS, BB), 256, 0, stream>>>(Qp, Kp, Vp, Cx);
  gemm_bt<bf16_t, float, float><<<gg, 256, 0, stream>>>(Cx, Wo, out, MROWS, EMB, EMB);
}

// Round 4
// 481.334 us; speedup vs baseline: 1.3722x; 1.3722x over previous
//
#include <hip/hip_runtime.h>
#include <hip/hip_bf16.h>

#define EMB   1024
#define HEADS 16
#define HDIM  64
#define BB    4
#define SS    2048
#define MROWS (BB*SS)   // 8192

typedef __bf16 bf16_t;
typedef __bf16 bf16x8 __attribute__((ext_vector_type(8)));
typedef float  f32x4  __attribute__((ext_vector_type(4)));

// async global->LDS, 16B/lane; LDS base wave-uniform, HW adds lane*16
__device__ __forceinline__ void glds16(const void* g, void* l) {
  __builtin_amdgcn_global_load_lds(
      (const __attribute__((address_space(1))) void*)g,
      (__attribute__((address_space(3))) void*)l, 16, 0, 0);
}

// ---------------------------------------------------------------------------
// Tile staging into LDS (128 rows x 32 cols), global_load_lds 16B/lane.
// fp32 tiles get an XOR colblock swizzle (phys = logical ^ 2*(row&3)) to break
// the 128B-row-stride bank degeneracy; bf16 tiles use the m97 layout as-is.
// ---------------------------------------------------------------------------
__device__ __forceinline__ void stage_tile(const float* src, size_t ld,
                                           float* lds, int wave, int lane) {
#pragma unroll
  for (int j = 0; j < 4; ++j) {
    const int i   = wave*4 + j;               // chunk 0..15 (256 f32 each)
    const int row = i*8 + (lane >> 3);
    const int col = ((lane & 7) ^ (((lane >> 3) & 3) << 1)) * 4;  // swizzled
    glds16(src + (size_t)row*ld + col, lds + i*256);
  }
}
__device__ __forceinline__ void stage_tile(const bf16_t* src, size_t ld,
                                           bf16_t* lds, int wave, int lane) {
#pragma unroll
  for (int j = 0; j < 2; ++j) {
    const int i   = wave*2 + j;               // chunk 0..7 (512 bf16 each)
    const int row = i*16 + (lane >> 2);
    const int col = (lane & 3) * 8;
    glds16(src + (size_t)row*ld + col, lds + i*512);
  }
}

// fragment read from staged tile (row-major 32-wide), cvt fp32->bf16 if needed
__device__ __forceinline__ bf16x8 frag(const bf16_t* lds, int row, int quad) {
  return *(const bf16x8*)&lds[row*32 + quad*8];
}
__device__ __forceinline__ bf16x8 frag(const float* lds, int row, int quad) {
  const int p = ((quad << 1) ^ ((row & 3) << 1));   // phys colblock (even)
  const f32x4 u = *(const f32x4*)&lds[row*32 + p*4];
  const f32x4 v = *(const f32x4*)&lds[row*32 + p*4 + 4];
  bf16x8 r;
  r[0]=(bf16_t)u[0]; r[1]=(bf16_t)u[1]; r[2]=(bf16_t)u[2]; r[3]=(bf16_t)u[3];
  r[4]=(bf16_t)v[0]; r[5]=(bf16_t)v[1]; r[6]=(bf16_t)v[2]; r[7]=(bf16_t)v[3];
  return r;
}

__device__ __forceinline__ void store_out(float* p, float v)  { *p = v; }
__device__ __forceinline__ void store_out(bf16_t* p, float v) { *p = (bf16_t)v; }

// ---------------------------------------------------------------------------
// C[M,N] = oscale * A[M,K] @ W[N,K]^T   (mixed fp32/bf16 in, fp32 acc)
// 128x128 tile, BK=32, glds staging, 16x16x32 bf16 MFMA (m97 structure).
// ---------------------------------------------------------------------------
template <typename TA, typename TW, typename TC>
__launch_bounds__(256)
__global__ void gemm_bt(const TA* __restrict__ A, const TW* __restrict__ W,
                        TC* __restrict__ C, int M, int N, int K, float oscale) {
  __shared__ __align__(16) TA As[128*32];
  __shared__ __align__(16) TW Bs[128*32];
  const int tid  = threadIdx.x;
  const int wave = tid >> 6, lane = tid & 63;
  const int quad = lane >> 4, l16 = lane & 15;
  const int wm = wave >> 1, wn = wave & 1;
  const int bm0 = blockIdx.y * 128, bn0 = blockIdx.x * 128;

  f32x4 acc[4][4] = {};

  for (int k0 = 0; k0 < K; k0 += 32) {
    stage_tile(A + (size_t)bm0*K + k0, K, As, wave, lane);
    stage_tile(W + (size_t)bn0*K + k0, K, Bs, wave, lane);
    __syncthreads();

    bf16x8 a[4], b[4];
#pragma unroll
    for (int t = 0; t < 4; ++t) {
      a[t] = frag(As, wm*64 + t*16 + l16, quad);
      b[t] = frag(Bs, wn*64 + t*16 + l16, quad);
    }
#pragma unroll
    for (int mt = 0; mt < 4; ++mt)
#pragma unroll
      for (int nt = 0; nt < 4; ++nt)
        acc[mt][nt] = __builtin_amdgcn_mfma_f32_16x16x32_bf16(a[mt], b[nt], acc[mt][nt], 0, 0, 0);
    __syncthreads();
  }

  // epilogue: C/D layout col=lane&15, row=quad*4+reg
#pragma unroll
  for (int mt = 0; mt < 4; ++mt) {
    const int row = bm0 + wm*64 + mt*16 + quad*4;
#pragma unroll
    for (int nt = 0; nt < 4; ++nt) {
      const int col = bn0 + wn*64 + nt*16 + l16;
#pragma unroll
      for (int r = 0; r < 4; ++r)
        store_out(&C[(size_t)(row + r)*N + col], acc[mt][nt][r] * oscale);
    }
  }
}

// ---------------------------------------------------------------------------
// V transpose: Vp[b][s][h*64+d] -> Vt[(b*H+h)*64+d][s]   (once per element)
// ---------------------------------------------------------------------------
__launch_bounds__(256)
__global__ void transpose_v(const bf16_t* __restrict__ Vp, bf16_t* __restrict__ Vt) {
  __shared__ bf16_t T[64][72];
  const int tid = threadIdx.x;
  const int b = blockIdx.z, h = blockIdx.y, s0 = blockIdx.x * 64;
#pragma unroll
  for (int c = 0; c < 2; ++c) {
    const int e  = (tid + c*256) * 8;
    const int rs = e >> 6, cd = e & 63;
    const bf16x8 v = *(const bf16x8*)&Vp[(size_t)(b*SS + s0 + rs)*EMB + h*HDIM + cd];
#pragma unroll
    for (int j = 0; j < 8; ++j) T[cd + j][rs] = v[j];
  }
  __syncthreads();
#pragma unroll
  for (int c = 0; c < 2; ++c) {
    const int e  = (tid + c*256) * 8;
    const int rd = e >> 6, cs = e & 63;
    *(bf16x8*)&Vt[(size_t)((b*HEADS + h)*HDIM + rd)*SS + s0 + cs] =
        *(const bf16x8*)&T[rd][cs];
  }
}

// ---------------------------------------------------------------------------
// Flash attention, Q-tile 128 (4 waves x 32 rows), K-tile 64.
// Q pre-scaled by 1/sqrt(64)*log2e in the projection epilogue; no-max
// softmax (scores bounded ~|40| << 127 in exp2 domain); deferred l-reduce.
// K/V staged via global_load_lds into half-split [2][64][32] layouts (m97
// read pattern); P round-trips wave-private LDS with XOR colblock swizzle.
// Qp and Cx alias (disjoint per-block row x head-col slices).
// ---------------------------------------------------------------------------
__launch_bounds__(256)
__global__ void attn(const bf16_t* Qp, const bf16_t* __restrict__ Kp,
                     const bf16_t* __restrict__ Vt, bf16_t* Cx) {
  __shared__ __align__(16) bf16_t Ks[2*64*32];     // [half][t][d-half]  8KB
  __shared__ __align__(16) bf16_t Vs[2*64*32];     // [half][d][t-half]  8KB
  __shared__ __align__(16) bf16_t Ps[4][2][1024];  // [wave][mb][half][q16][32] 16KB

  const int tid  = threadIdx.x;
  const int wave = tid >> 6, lane = tid & 63;
  const int quad = lane >> 4, l16 = lane & 15;
  const int b = blockIdx.z, h = blockIdx.y;
  const int q0 = blockIdx.x * 128;

  // Q fragments (A-operand, pre-scaled): wave handles rows q0+wave*32..+32
  bf16x8 qf[2][2];
#pragma unroll
  for (int mb = 0; mb < 2; ++mb) {
    const size_t qr = (size_t)(b*SS + q0 + wave*32 + mb*16 + l16)*EMB + h*HDIM;
#pragma unroll
    for (int ks = 0; ks < 2; ++ks)
      qf[mb][ks] = *(const bf16x8*)&Qp[qr + ks*32 + quad*8];
  }

  const bf16_t* Kbase = Kp + (size_t)b*SS*EMB + h*HDIM;
  const bf16_t* Vbase = Vt + (size_t)(b*HEADS + h)*HDIM*SS;

  f32x4 o[2][4] = {};
  float lsum[2][4] = {};

  for (int t0 = 0; t0 < SS; t0 += 64) {
    // stage K and V^T halves: 8 chunks each, wave does chunks {wave, wave+4}
#pragma unroll
    for (int c = 0; c < 2; ++c) {
      const int i    = wave + c*4;
      const int half = c;                       // i>>2 == c for wave<4
      const int r    = (i & 3)*16 + (lane >> 2);
      const int col  = (lane & 3)*8;
      glds16(Kbase + (size_t)(t0 + r)*EMB + half*32 + col, &Ks[i*512]);
      glds16(Vbase + (size_t)r*SS + t0 + half*32 + col,    &Vs[i*512]);
    }
    __syncthreads();

    // S = Q K^T  (16 MFMA)
    bf16x8 kf[4][2];
#pragma unroll
    for (int cb = 0; cb < 4; ++cb)
#pragma unroll
      for (int ks = 0; ks < 2; ++ks)
        kf[cb][ks] = *(const bf16x8*)&Ks[ks*2048 + (cb*16 + l16)*32 + quad*8];
    f32x4 s[2][4] = {};
#pragma unroll
    for (int mb = 0; mb < 2; ++mb)
#pragma unroll
      for (int cb = 0; cb < 4; ++cb)
#pragma unroll
        for (int ks = 0; ks < 2; ++ks)
          s[mb][cb] = __builtin_amdgcn_mfma_f32_16x16x32_bf16(qf[mb][ks], kf[cb][ks], s[mb][cb], 0, 0, 0);

    // no-max softmax: p = exp2(s); accumulate per-lane partial row sums
#pragma unroll
    for (int mb = 0; mb < 2; ++mb) {
      bf16_t* pw = Ps[wave][mb];
#pragma unroll
      for (int r = 0; r < 4; ++r) {
        float p[4];
#pragma unroll
        for (int cb = 0; cb < 4; ++cb) p[cb] = exp2f(s[mb][cb][r]);
        lsum[mb][r] += (p[0] + p[1]) + (p[2] + p[3]);
        const int rowoff = (quad*4 + r)*32;
#pragma unroll
        for (int cb = 0; cb < 4; ++cb) {
          const int phys = (((cb & 1)*2 + (l16 >> 3)) ^ quad);   // XOR swizzle
          pw[(cb >> 1)*512 + rowoff + phys*8 + (l16 & 7)] = (bf16_t)p[cb];
        }
      }
    }
    // no barrier: Ps is wave-private (DS ops in-order within a wave)

    // O += P V  (16 MFMA)
#pragma unroll
    for (int ks = 0; ks < 2; ++ks) {
      bf16x8 vf[4];
#pragma unroll
      for (int nb = 0; nb < 4; ++nb)
        vf[nb] = *(const bf16x8*)&Vs[ks*2048 + (nb*16 + l16)*32 + quad*8];
#pragma unroll
      for (int mb = 0; mb < 2; ++mb) {
        const int phys = (quad ^ (l16 >> 2));                    // XOR swizzle
        const bf16x8 pf = *(const bf16x8*)&Ps[wave][mb][ks*512 + l16*32 + phys*8];
#pragma unroll
        for (int nb = 0; nb < 4; ++nb)
          o[mb][nb] = __builtin_amdgcn_mfma_f32_16x16x32_bf16(pf, vf[nb], o[mb][nb], 0, 0, 0);
      }
    }
    __syncthreads();   // protect Ks/Vs before next staging
  }

  // deferred l-reduction (over the 16 l16-lanes sharing each row) + write
#pragma unroll
  for (int mb = 0; mb < 2; ++mb)
#pragma unroll
    for (int r = 0; r < 4; ++r) {
      float l = lsum[mb][r];
#pragma unroll
      for (int m = 1; m < 16; m <<= 1) l += __shfl_xor(l, m, 64);
      const float inv = 1.0f / l;
      const size_t row = (size_t)(b*SS + q0 + wave*32 + mb*16 + quad*4 + r)*EMB + h*HDIM;
#pragma unroll
      for (int nb = 0; nb < 4; ++nb)
        Cx[row + nb*16 + l16] = (bf16_t)(o[mb][nb][r] * inv);
    }
}

// ---------------------------------------------------------------------------
extern "C" void kernel_launch(void* const* d_in, const int* in_sizes, int n_in,
                              void* d_out, int out_size, void* d_ws, size_t ws_size,
                              hipStream_t stream) {
  (void)in_sizes; (void)n_in; (void)out_size; (void)ws_size;
  const float* query = (const float*)d_in[0];
  const float* key   = (const float*)d_in[1];
  const float* value = (const float*)d_in[2];
  const float* Wq    = (const float*)d_in[3];
  const float* Wk    = (const float*)d_in[4];
  const float* Wv    = (const float*)d_in[5];
  const float* Wo    = (const float*)d_in[6];

  // ws (32MB): Qp | Kp.  d_out (33.6MB fp32): Vp | Vt as bf16 scratch (dead
  // before the final GEMM overwrites d_out).  Cx aliases Qp (disjoint
  // per-block slices, read-before-write).
  bf16_t* Qp = (bf16_t*)d_ws;
  bf16_t* Kp = Qp + (size_t)MROWS*EMB;
  bf16_t* Vp = (bf16_t*)d_out;
  bf16_t* Vt = Vp + (size_t)MROWS*EMB;
  bf16_t* Cx = Qp;
  float*  out = (float*)d_out;

  const float sscale = 0.125f * 1.44269504f;  // 1/sqrt(64) * log2(e), folded into Q

  const dim3 gg(EMB/128, MROWS/128);  // (8, 64) = 512 blocks
  gemm_bt<float, float, bf16_t><<<gg, 256, 0, stream>>>(query, Wq, Qp, MROWS, EMB, EMB, sscale);
  gemm_bt<float, float, bf16_t><<<gg, 256, 0, stream>>>(key,   Wk, Kp, MROWS, EMB, EMB, 1.0f);
  gemm_bt<float, float, bf16_t><<<gg, 256, 0, stream>>>(value, Wv, Vp, MROWS, EMB, EMB, 1.0f);
  transpose_v<<<dim3(SS/64, HEADS, BB), 256, 0, stream>>>(Vp, Vt);
  attn<<<dim3(SS/128, HEADS, BB), 256, 0, stream>>>(Qp, Kp, Vt, Cx);
  gemm_bt<bf16_t, float, float><<<gg, 256, 0, stream>>>(Cx, Wo, out, MROWS, EMB, EMB, 1.0f);
}

// Round 5
// 372.736 us; speedup vs baseline: 1.7720x; 1.2914x over previous
//
#include <hip/hip_runtime.h>
#include <hip/hip_bf16.h>

#define EMB   1024
#define HEADS 16
#define HDIM  64
#define BB    4
#define SS    2048
#define MROWS (BB*SS)   // 8192

typedef __bf16 bf16_t;
typedef __bf16 bf16x4_t __attribute__((ext_vector_type(4)));
typedef __bf16 bf16x8   __attribute__((ext_vector_type(8)));
typedef float  f32x4    __attribute__((ext_vector_type(4)));

// async global->LDS, 16B/lane; LDS base wave-uniform, HW adds lane*16
__device__ __forceinline__ void glds16(const void* g, void* l) {
  __builtin_amdgcn_global_load_lds(
      (const __attribute__((address_space(1))) void*)g,
      (__attribute__((address_space(3))) void*)l, 16, 0, 0);
}

// ---------------------------------------------------------------------------
// fp32 -> bf16 cast, 8 elems/thread, fully coalesced
// ---------------------------------------------------------------------------
__launch_bounds__(256)
__global__ void cast_f32_bf16(const float* __restrict__ src, bf16_t* __restrict__ dst) {
  const int i = (blockIdx.x*256 + threadIdx.x) * 8;
  const f32x4 a = *(const f32x4*)&src[i];
  const f32x4 b = *(const f32x4*)&src[i+4];
  bf16x8 r;
  r[0]=(bf16_t)a[0]; r[1]=(bf16_t)a[1]; r[2]=(bf16_t)a[2]; r[3]=(bf16_t)a[3];
  r[4]=(bf16_t)b[0]; r[5]=(bf16_t)b[1]; r[6]=(bf16_t)b[2]; r[7]=(bf16_t)b[3];
  *(bf16x8*)&dst[i] = r;
}

// ---------------------------------------------------------------------------
// C[M,N] = oscale * A[M,K] @ W[N,K]^T, pure bf16 (m97 structure):
// 128x128 tile, BK=32, glds16 staging, 16 MFMA 16x16x32_bf16 per K-step.
// VEPI=0: row-major C (TC = bf16 or float).
// VEPI=1: packed-V^T epilogue for attention (C = Vt, layout per (b,h,T=64keys):
//         4096-elem blocks of 16B chunks [g=dt*2+ks][q][l16] where chunk =
//         {V^T[d][32ks+4q+0..3], V^T[d][32ks+16+4q+0..3]}, d = dt*16+l16).
// ---------------------------------------------------------------------------
template <int VEPI, typename TC>
__launch_bounds__(256)
__global__ void gemm_bt(const bf16_t* __restrict__ A, const bf16_t* __restrict__ W,
                        TC* __restrict__ C, float oscale) {
  __shared__ __align__(16) bf16_t As[128*32];
  __shared__ __align__(16) bf16_t Bs[128*32];
  const int tid  = threadIdx.x;
  const int wave = tid >> 6, lane = tid & 63;
  const int quad = lane >> 4, l16 = lane & 15;
  const int wm = wave >> 1, wn = wave & 1;
  const int bm0 = blockIdx.y * 128, bn0 = blockIdx.x * 128;

  f32x4 acc[4][4] = {};

  for (int k0 = 0; k0 < EMB; k0 += 32) {
#pragma unroll
    for (int j = 0; j < 2; ++j) {
      const int i   = wave*2 + j;              // chunk 0..7 (512 bf16 = 1KB)
      const int row = i*16 + (lane >> 2);
      const int col = (lane & 3) * 8;
      glds16(A + (size_t)(bm0 + row)*EMB + k0 + col, &As[i*512]);
      glds16(W + (size_t)(bn0 + row)*EMB + k0 + col, &Bs[i*512]);
    }
    __syncthreads();

    bf16x8 a[4], b[4];
#pragma unroll
    for (int t = 0; t < 4; ++t) {
      a[t] = *(const bf16x8*)&As[(wm*64 + t*16 + l16)*32 + quad*8];
      b[t] = *(const bf16x8*)&Bs[(wn*64 + t*16 + l16)*32 + quad*8];
    }
#pragma unroll
    for (int mt = 0; mt < 4; ++mt)
#pragma unroll
      for (int nt = 0; nt < 4; ++nt)
        acc[mt][nt] = __builtin_amdgcn_mfma_f32_16x16x32_bf16(a[mt], b[nt], acc[mt][nt], 0, 0, 0);
    __syncthreads();
  }

  if (VEPI) {
    // packed-V^T epilogue: acc[mt][nt][r] = V[s = bm0+wm*64+mt*16+quad*4+r][col]
    // = V^T[d][s]; chunk(ks,nt) = {acc[2ks][nt][0..3], acc[2ks+1][nt][0..3]}
    const int bb = bm0 >> 11;                    // batch (2048 rows each)
    const int T  = ((bm0 & 2047) >> 6) + wm;     // 64-key tile within batch
    const int h  = (bn0 >> 6) + wn;              // head (64 cols each)
    bf16_t* base = (bf16_t*)C + ((size_t)(bb*HEADS + h)*32 + T)*4096;
#pragma unroll
    for (int ks = 0; ks < 2; ++ks)
#pragma unroll
      for (int nt = 0; nt < 4; ++nt) {
        bf16x8 v;
#pragma unroll
        for (int r = 0; r < 4; ++r) {
          v[r]     = (bf16_t)acc[2*ks][nt][r];
          v[4 + r] = (bf16_t)acc[2*ks + 1][nt][r];
        }
        *(bf16x8*)&base[((nt*2 + ks)*64 + quad*16 + l16)*8] = v;
      }
  } else {
    // generic row-major epilogue: C/D layout col=l16, row=quad*4+reg
#pragma unroll
    for (int mt = 0; mt < 4; ++mt) {
      const int row = bm0 + wm*64 + mt*16 + quad*4;
#pragma unroll
      for (int nt = 0; nt < 4; ++nt) {
        const int col = bn0 + wn*64 + nt*16 + l16;
#pragma unroll
        for (int r = 0; r < 4; ++r)
          C[(size_t)(row + r)*EMB + col] = (TC)(acc[mt][nt][r] * oscale);
      }
    }
  }
}

// ---------------------------------------------------------------------------
// Flash attention, Q-tile 128 (4 waves x 32 rows), K-tile 64, no P LDS
// round-trip:  S^T = MFMA(A=K, B=Q)  ->  C-layout = lane:qrow, regs:4 keys
// which IS the B-operand (P^T) layout of  O^T = MFMA(A=V^T, B=P^T)  when V^T
// is staged in the packed chunk order produced by the V-GEMM epilogue.
// No-max softmax (|scaled scores| ~< 9 << 127 exp2 range; scale folded into
// Q projection), raw v_exp_f32, deferred l-reduction.
// Qp and Cx alias (disjoint per-block row x head-col slices, read-before-write).
// ---------------------------------------------------------------------------
__launch_bounds__(256)
__global__ void attn(const bf16_t* Qp, const bf16_t* __restrict__ Kp,
                     const bf16_t* __restrict__ Vt, bf16_t* Cx) {
  __shared__ __align__(16) bf16_t Ks[2*64*32];  // [d-half][key][32]   8KB
  __shared__ __align__(16) bf16_t Vs[4096];     // packed V^T chunks   8KB

  const int tid  = threadIdx.x;
  const int wave = tid >> 6, lane = tid & 63;
  const int quad = lane >> 4, l16 = lane & 15;
  const int b = blockIdx.z, h = blockIdx.y;
  const int q0 = blockIdx.x * 128;

  // Q fragments (B-operand of S^T): lane l16 = qrow, k = d = quad*8+j (+32ks)
  bf16x8 qf[2][2];
#pragma unroll
  for (int mb = 0; mb < 2; ++mb) {
    const size_t qr = (size_t)(b*SS + q0 + wave*32 + mb*16 + l16)*EMB + h*HDIM;
#pragma unroll
    for (int ks = 0; ks < 2; ++ks)
      qf[mb][ks] = *(const bf16x8*)&Qp[qr + ks*32 + quad*8];
  }

  const bf16_t* Kb = Kp + (size_t)b*SS*EMB + h*HDIM;
  const bf16_t* Vb = Vt + ((size_t)(b*HEADS + h)*32)*4096;

  f32x4 o[2][4] = {};          // O^T: lane l16 = qrow, row = d = quad*4+r
  float lsum[2] = {0.f, 0.f};

  for (int t0 = 0; t0 < SS; t0 += 64) {
    // stage K (row-major halves) + packed V^T (identity copy): 4 glds16/wave
#pragma unroll
    for (int c = 0; c < 2; ++c) {
      const int i   = wave + c*4;
      const int r   = (i & 3)*16 + (lane >> 2);
      const int col = (lane & 3)*8;
      glds16(Kb + (size_t)(t0 + r)*EMB + c*32 + col, &Ks[i*512]);
      glds16(Vb + (size_t)(t0 >> 6)*4096 + i*512 + lane*8, &Vs[i*512]);
    }
    __syncthreads();

    // S^T = K Q^T : A = K-frag (lane l16 = key), B = Q-frag  (16 MFMA)
    f32x4 st[2][4] = {};
#pragma unroll
    for (int cb = 0; cb < 4; ++cb) {
      const bf16x8 kf0 = *(const bf16x8*)&Ks[(cb*16 + l16)*32 + quad*8];
      const bf16x8 kf1 = *(const bf16x8*)&Ks[2048 + (cb*16 + l16)*32 + quad*8];
#pragma unroll
      for (int mb = 0; mb < 2; ++mb) {
        st[mb][cb] = __builtin_amdgcn_mfma_f32_16x16x32_bf16(kf0, qf[mb][0], st[mb][cb], 0, 0, 0);
        st[mb][cb] = __builtin_amdgcn_mfma_f32_16x16x32_bf16(kf1, qf[mb][1], st[mb][cb], 0, 0, 0);
      }
    }

    // softmax (no-max): p = exp2(s); pack P^T B-fragments directly from regs
    bf16x8 pb[2][2];
#pragma unroll
    for (int mb = 0; mb < 2; ++mb) {
      float ls = 0.f;
#pragma unroll
      for (int kb = 0; kb < 4; ++kb)
#pragma unroll
        for (int r = 0; r < 4; ++r) {
          const float p = __builtin_amdgcn_exp2f(st[mb][kb][r]);
          st[mb][kb][r] = p;
          ls += p;
        }
      lsum[mb] += ls;
#pragma unroll
      for (int ks = 0; ks < 2; ++ks)
#pragma unroll
        for (int r = 0; r < 4; ++r) {
          pb[mb][ks][r]     = (bf16_t)st[mb][2*ks][r];
          pb[mb][ks][4 + r] = (bf16_t)st[mb][2*ks + 1][r];
        }
    }

    // O^T += V^T P^T : A = packed V^T chunk, B = pb  (16 MFMA)
#pragma unroll
    for (int ks = 0; ks < 2; ++ks)
#pragma unroll
      for (int dt = 0; dt < 4; ++dt) {
        const bf16x8 vf = *(const bf16x8*)&Vs[((dt*2 + ks)*64 + quad*16 + l16)*8];
#pragma unroll
        for (int mb = 0; mb < 2; ++mb)
          o[mb][dt] = __builtin_amdgcn_mfma_f32_16x16x32_bf16(vf, pb[mb][ks], o[mb][dt], 0, 0, 0);
      }
    __syncthreads();   // protect Ks/Vs before next staging
  }

  // l-reduce across quads (lanes sharing l16) + write O^T as [row][h*64+d]
#pragma unroll
  for (int mb = 0; mb < 2; ++mb) {
    float l = lsum[mb];
    l += __shfl_xor(l, 16, 64);
    l += __shfl_xor(l, 32, 64);
    const float inv = 1.0f / l;
    const size_t row = (size_t)(b*SS + q0 + wave*32 + mb*16 + l16)*EMB + h*HDIM;
#pragma unroll
    for (int dt = 0; dt < 4; ++dt) {
      bf16x4_t v;
#pragma unroll
      for (int r = 0; r < 4; ++r) v[r] = (bf16_t)(o[mb][dt][r] * inv);
      *(bf16x4_t*)&Cx[row + dt*16 + quad*4] = v;
    }
  }
}

// ---------------------------------------------------------------------------
extern "C" void kernel_launch(void* const* d_in, const int* in_sizes, int n_in,
                              void* d_out, int out_size, void* d_ws, size_t ws_size,
                              hipStream_t stream) {
  (void)in_sizes; (void)n_in; (void)out_size; (void)ws_size;
  const float* query = (const float*)d_in[0];
  const float* key   = (const float*)d_in[1];
  const float* value = (const float*)d_in[2];
  const float* WqF   = (const float*)d_in[3];
  const float* WkF   = (const float*)d_in[4];
  const float* WvF   = (const float*)d_in[5];
  const float* WoF   = (const float*)d_in[6];

  // ws (40MB): S1(16) | S2(16) | W(8).  d_out (33.55MB): S5(16) | S6(16) as
  // bf16 scratch, both dead before the final fp32 GEMM overwrites d_out.
  // Sequence keeps only {S1,S2,W} + d_out halves live at any point:
  //   qb->S1, Qp->S2, kb->S1, Kp->S6, vb->S5, Vt->S1, Cx alias Qp(S2).
  bf16_t* S1  = (bf16_t*)d_ws;
  bf16_t* S2  = S1 + (size_t)MROWS*EMB;
  bf16_t* Wqb = S2 + (size_t)MROWS*EMB;
  bf16_t* Wkb = Wqb + (size_t)EMB*EMB;
  bf16_t* Wvb = Wkb + (size_t)EMB*EMB;
  bf16_t* Wob = Wvb + (size_t)EMB*EMB;
  bf16_t* S5  = (bf16_t*)d_out;
  bf16_t* S6  = S5 + (size_t)MROWS*EMB;
  float*  out = (float*)d_out;

  const float sscale = 0.125f * 1.44269504f;  // 1/sqrt(64)*log2(e) into Q

  const dim3 cw(EMB*EMB/(256*8));   // 512 blocks per weight cast
  const dim3 ca((size_t)MROWS*EMB/(256*8));  // 4096 blocks per activation cast
  const dim3 gg(EMB/128, MROWS/128);         // (8, 64)

  cast_f32_bf16<<<cw, 256, 0, stream>>>(WqF, Wqb);
  cast_f32_bf16<<<cw, 256, 0, stream>>>(WkF, Wkb);
  cast_f32_bf16<<<cw, 256, 0, stream>>>(WvF, Wvb);
  cast_f32_bf16<<<cw, 256, 0, stream>>>(WoF, Wob);

  cast_f32_bf16<<<ca, 256, 0, stream>>>(query, S1);
  gemm_bt<0, bf16_t><<<gg, 256, 0, stream>>>(S1, Wqb, S2, sscale);   // Qp=S2

  cast_f32_bf16<<<ca, 256, 0, stream>>>(key, S1);
  gemm_bt<0, bf16_t><<<gg, 256, 0, stream>>>(S1, Wkb, S6, 1.0f);     // Kp=S6

  cast_f32_bf16<<<ca, 256, 0, stream>>>(value, S5);
  gemm_bt<1, bf16_t><<<gg, 256, 0, stream>>>(S5, Wvb, S1, 1.0f);     // Vt=S1 (packed)

  attn<<<dim3(SS/128, HEADS, BB), 256, 0, stream>>>(S2, S6, S1, S2); // Cx=S2

  gemm_bt<0, float><<<gg, 256, 0, stream>>>(S2, Wob, out, 1.0f);
}

// Round 6
// 365.107 us; speedup vs baseline: 1.8090x; 1.0209x over previous
//
#include <hip/hip_runtime.h>
#include <hip/hip_bf16.h>

#define EMB   1024
#define HEADS 16
#define HDIM  64
#define BB    4
#define SS    2048
#define MROWS (BB*SS)   // 8192

typedef __bf16 bf16_t;
typedef __bf16 bf16x4_t __attribute__((ext_vector_type(4)));
typedef __bf16 bf16x8   __attribute__((ext_vector_type(8)));
typedef float  f32x4    __attribute__((ext_vector_type(4)));

// async global->LDS, 16B/lane; LDS base wave-uniform, HW adds lane*16
__device__ __forceinline__ void glds16(const void* g, void* l) {
  __builtin_amdgcn_global_load_lds(
      (const __attribute__((address_space(1))) void*)g,
      (__attribute__((address_space(3))) void*)l, 16, 0, 0);
}

// ---------------------------------------------------------------------------
// Multi-tensor fp32->bf16 cast. z < nact: 8M-elem activations (4096 blocks);
// z >= nact: 1M-elem weights (first 512 blocks active).
// ---------------------------------------------------------------------------
__launch_bounds__(256)
__global__ void cast_multi(const float* s0, const float* s1, const float* s2,
                           const float* s3, const float* s4, const float* s5,
                           const float* s6,
                           bf16_t* d0, bf16_t* d1, bf16_t* d2, bf16_t* d3,
                           bf16_t* d4, bf16_t* d5, bf16_t* d6, int nact) {
  const int z = blockIdx.z;
  if (z >= nact && blockIdx.x >= 512) return;
  const float* ss[7] = {s0, s1, s2, s3, s4, s5, s6};
  bf16_t*      dd[7] = {d0, d1, d2, d3, d4, d5, d6};
  const float* s = ss[z];
  bf16_t*      d = dd[z];
  const int i = (blockIdx.x*256 + threadIdx.x) * 8;
  const f32x4 a = *(const f32x4*)&s[i];
  const f32x4 b = *(const f32x4*)&s[i+4];
  bf16x8 r;
  r[0]=(bf16_t)a[0]; r[1]=(bf16_t)a[1]; r[2]=(bf16_t)a[2]; r[3]=(bf16_t)a[3];
  r[4]=(bf16_t)b[0]; r[5]=(bf16_t)b[1]; r[6]=(bf16_t)b[2]; r[7]=(bf16_t)b[3];
  *(bf16x8*)&d[i] = r;
}

__launch_bounds__(256)
__global__ void cast_f32_bf16(const float* __restrict__ src, bf16_t* __restrict__ dst) {
  const int i = (blockIdx.x*256 + threadIdx.x) * 8;
  const f32x4 a = *(const f32x4*)&src[i];
  const f32x4 b = *(const f32x4*)&src[i+4];
  bf16x8 r;
  r[0]=(bf16_t)a[0]; r[1]=(bf16_t)a[1]; r[2]=(bf16_t)a[2]; r[3]=(bf16_t)a[3];
  r[4]=(bf16_t)b[0]; r[5]=(bf16_t)b[1]; r[6]=(bf16_t)b[2]; r[7]=(bf16_t)b[3];
  *(bf16x8*)&dst[i] = r;
}

// ---------------------------------------------------------------------------
// Shared GEMM core: acc[4][4] += A_tile @ W_tile^T over full K=EMB.
// 128x128 tile, BK=32, glds16 staging, 16 MFMA/K-step (m97 structure).
// ---------------------------------------------------------------------------
__device__ __forceinline__ void gemm_core(const bf16_t* __restrict__ A,
                                          const bf16_t* __restrict__ W,
                                          bf16_t* As, bf16_t* Bs,
                                          f32x4 acc[4][4],
                                          int bm0, int bn0,
                                          int wave, int lane) {
  const int quad = lane >> 4, l16 = lane & 15;
  const int wm = wave >> 1, wn = wave & 1;
  for (int k0 = 0; k0 < EMB; k0 += 32) {
#pragma unroll
    for (int j = 0; j < 2; ++j) {
      const int i   = wave*2 + j;              // chunk 0..7 (512 bf16 = 1KB)
      const int row = i*16 + (lane >> 2);
      const int col = (lane & 3) * 8;
      glds16(A + (size_t)(bm0 + row)*EMB + k0 + col, &As[i*512]);
      glds16(W + (size_t)(bn0 + row)*EMB + k0 + col, &Bs[i*512]);
    }
    __syncthreads();

    bf16x8 a[4], b[4];
#pragma unroll
    for (int t = 0; t < 4; ++t) {
      a[t] = *(const bf16x8*)&As[(wm*64 + t*16 + l16)*32 + quad*8];
      b[t] = *(const bf16x8*)&Bs[(wn*64 + t*16 + l16)*32 + quad*8];
    }
#pragma unroll
    for (int mt = 0; mt < 4; ++mt)
#pragma unroll
      for (int nt = 0; nt < 4; ++nt)
        acc[mt][nt] = __builtin_amdgcn_mfma_f32_16x16x32_bf16(a[mt], b[nt], acc[mt][nt], 0, 0, 0);
    __syncthreads();
  }
}

// ---------------------------------------------------------------------------
// Fused projection GEMM. z = blockIdx.z + zbase selects (A, W, C, epilogue):
//   z=0: Q — row-major, scaled by sscale
//   z=1: K — row-major
//   z=2: V — packed-V^T epilogue (attention B-operand chunk order)
// ---------------------------------------------------------------------------
__launch_bounds__(256)
__global__ void gemm_qkv(const bf16_t* A0, const bf16_t* A1, const bf16_t* A2,
                         const bf16_t* W0, const bf16_t* W1, const bf16_t* W2,
                         bf16_t* C0, bf16_t* C1, bf16_t* C2,
                         float sscale, int zbase) {
  __shared__ __align__(16) bf16_t As[128*32];
  __shared__ __align__(16) bf16_t Bs[128*32];
  const int tid  = threadIdx.x;
  const int wave = tid >> 6, lane = tid & 63;
  const int quad = lane >> 4, l16 = lane & 15;
  const int wm = wave >> 1, wn = wave & 1;
  const int bm0 = blockIdx.y * 128, bn0 = blockIdx.x * 128;
  const int z = blockIdx.z + zbase;

  const bf16_t* A = (z == 0) ? A0 : (z == 1) ? A1 : A2;
  const bf16_t* W = (z == 0) ? W0 : (z == 1) ? W1 : W2;
  bf16_t*       C = (z == 0) ? C0 : (z == 1) ? C1 : C2;
  const float oscale = (z == 0) ? sscale : 1.0f;

  f32x4 acc[4][4] = {};
  gemm_core(A, W, As, Bs, acc, bm0, bn0, wave, lane);

  if (z == 2) {
    // packed-V^T epilogue: acc[mt][nt][r] = V[s=bm0+wm*64+mt*16+quad*4+r][d]
    // chunk(ks,nt) = {acc[2ks][nt][0..3], acc[2ks+1][nt][0..3]}
    const int bb = bm0 >> 11;                    // batch (2048 rows each)
    const int T  = ((bm0 & 2047) >> 6) + wm;     // 64-key tile within batch
    const int h  = (bn0 >> 6) + wn;              // head (64 cols each)
    bf16_t* base = C + ((size_t)(bb*HEADS + h)*32 + T)*4096;
#pragma unroll
    for (int ks = 0; ks < 2; ++ks)
#pragma unroll
      for (int nt = 0; nt < 4; ++nt) {
        bf16x8 v;
#pragma unroll
        for (int r = 0; r < 4; ++r) {
          v[r]     = (bf16_t)acc[2*ks][nt][r];
          v[4 + r] = (bf16_t)acc[2*ks + 1][nt][r];
        }
        *(bf16x8*)&base[((nt*2 + ks)*64 + quad*16 + l16)*8] = v;
      }
  } else {
    // row-major epilogue: C/D layout col=l16, row=quad*4+reg
#pragma unroll
    for (int mt = 0; mt < 4; ++mt) {
      const int row = bm0 + wm*64 + mt*16 + quad*4;
#pragma unroll
      for (int nt = 0; nt < 4; ++nt) {
        const int col = bn0 + wn*64 + nt*16 + l16;
#pragma unroll
        for (int r = 0; r < 4; ++r)
          C[(size_t)(row + r)*EMB + col] = (bf16_t)(acc[mt][nt][r] * oscale);
      }
    }
  }
}

// output GEMM: fp32 C, row-major
__launch_bounds__(256)
__global__ void gemm_out(const bf16_t* __restrict__ A, const bf16_t* __restrict__ W,
                         float* __restrict__ C) {
  __shared__ __align__(16) bf16_t As[128*32];
  __shared__ __align__(16) bf16_t Bs[128*32];
  const int tid  = threadIdx.x;
  const int wave = tid >> 6, lane = tid & 63;
  const int quad = lane >> 4, l16 = lane & 15;
  const int wm = wave >> 1, wn = wave & 1;
  const int bm0 = blockIdx.y * 128, bn0 = blockIdx.x * 128;

  f32x4 acc[4][4] = {};
  gemm_core(A, W, As, Bs, acc, bm0, bn0, wave, lane);

#pragma unroll
  for (int mt = 0; mt < 4; ++mt) {
    const int row = bm0 + wm*64 + mt*16 + quad*4;
#pragma unroll
    for (int nt = 0; nt < 4; ++nt) {
      const int col = bn0 + wn*64 + nt*16 + l16;
#pragma unroll
      for (int r = 0; r < 4; ++r)
        C[(size_t)(row + r)*EMB + col] = acc[mt][nt][r];
    }
  }
}

// ---------------------------------------------------------------------------
// Flash attention, Q-tile 128 (4 waves x 32 rows), 128-key staging tiles
// (two 64-key subtiles per barrier pair).  S^T = MFMA(A=K, B=Q) produces the
// P^T B-operand layout directly (regs = 4 keys, lane = qrow); packed V^T from
// the V-GEMM epilogue serves as the A-operand of O^T = V^T P^T with zero data
// movement.  No-max softmax (scale folded into Q projection; |s| << 127),
// raw v_exp_f32, deferred l-reduction.
// Qp and Cx alias (disjoint per-block slices, read-before-write).
// ---------------------------------------------------------------------------
__launch_bounds__(256)
__global__ void attn(const bf16_t* Qp, const bf16_t* __restrict__ Kp,
                     const bf16_t* __restrict__ Vt, bf16_t* Cx) {
  __shared__ __align__(16) bf16_t Ks[2*4096];   // [sub][d-half][key][32] 16KB
  __shared__ __align__(16) bf16_t Vs[2*4096];   // [sub][packed chunks]   16KB

  const int tid  = threadIdx.x;
  const int wave = tid >> 6, lane = tid & 63;
  const int quad = lane >> 4, l16 = lane & 15;
  const int b = blockIdx.z, h = blockIdx.y;
  const int q0 = blockIdx.x * 128;

  // Q fragments (B-operand of S^T): lane l16 = qrow, k = d = quad*8+j (+32ks)
  bf16x8 qf[2][2];
#pragma unroll
  for (int mb = 0; mb < 2; ++mb) {
    const size_t qr = (size_t)(b*SS + q0 + wave*32 + mb*16 + l16)*EMB + h*HDIM;
#pragma unroll
    for (int ks = 0; ks < 2; ++ks)
      qf[mb][ks] = *(const bf16x8*)&Qp[qr + ks*32 + quad*8];
  }

  const bf16_t* Kb = Kp + (size_t)b*SS*EMB + h*HDIM;
  const bf16_t* Vb = Vt + ((size_t)(b*HEADS + h)*32)*4096;

  f32x4 o[2][4] = {};          // O^T: lane l16 = qrow, row = d = quad*4+r
  float lsum[2] = {0.f, 0.f};

  for (int t0 = 0; t0 < SS; t0 += 128) {
    // stage 2 subtiles of 64 keys: 8 glds16/wave
#pragma unroll
    for (int sub = 0; sub < 2; ++sub)
#pragma unroll
      for (int c = 0; c < 2; ++c) {
        const int i   = wave + c*4;
        const int r   = (i & 3)*16 + (lane >> 2);
        const int col = (lane & 3)*8;
        glds16(Kb + (size_t)(t0 + sub*64 + r)*EMB + c*32 + col, &Ks[sub*4096 + i*512]);
        glds16(Vb + (size_t)((t0 >> 6) + sub)*4096 + i*512 + lane*8, &Vs[sub*4096 + i*512]);
      }
    __syncthreads();

#pragma unroll
    for (int sub = 0; sub < 2; ++sub) {
      const bf16_t* Kss = &Ks[sub*4096];
      const bf16_t* Vss = &Vs[sub*4096];

      // S^T = K Q^T : A = K-frag (lane l16 = key), B = Q-frag  (16 MFMA)
      f32x4 st[2][4] = {};
#pragma unroll
      for (int cb = 0; cb < 4; ++cb) {
        const bf16x8 kf0 = *(const bf16x8*)&Kss[(cb*16 + l16)*32 + quad*8];
        const bf16x8 kf1 = *(const bf16x8*)&Kss[2048 + (cb*16 + l16)*32 + quad*8];
#pragma unroll
        for (int mb = 0; mb < 2; ++mb) {
          st[mb][cb] = __builtin_amdgcn_mfma_f32_16x16x32_bf16(kf0, qf[mb][0], st[mb][cb], 0, 0, 0);
          st[mb][cb] = __builtin_amdgcn_mfma_f32_16x16x32_bf16(kf1, qf[mb][1], st[mb][cb], 0, 0, 0);
        }
      }

      // softmax (no-max): p = exp2(s); pack P^T B-fragments from regs
      bf16x8 pb[2][2];
#pragma unroll
      for (int mb = 0; mb < 2; ++mb) {
        float ls = 0.f;
#pragma unroll
        for (int kb = 0; kb < 4; ++kb)
#pragma unroll
          for (int r = 0; r < 4; ++r) {
            const float p = __builtin_amdgcn_exp2f(st[mb][kb][r]);
            st[mb][kb][r] = p;
            ls += p;
          }
        lsum[mb] += ls;
#pragma unroll
        for (int ks = 0; ks < 2; ++ks)
#pragma unroll
          for (int r = 0; r < 4; ++r) {
            pb[mb][ks][r]     = (bf16_t)st[mb][2*ks][r];
            pb[mb][ks][4 + r] = (bf16_t)st[mb][2*ks + 1][r];
          }
      }

      // O^T += V^T P^T : A = packed V^T chunk, B = pb  (16 MFMA)
#pragma unroll
      for (int ks = 0; ks < 2; ++ks)
#pragma unroll
        for (int dt = 0; dt < 4; ++dt) {
          const bf16x8 vf = *(const bf16x8*)&Vss[((dt*2 + ks)*64 + quad*16 + l16)*8];
#pragma unroll
          for (int mb = 0; mb < 2; ++mb)
            o[mb][dt] = __builtin_amdgcn_mfma_f32_16x16x32_bf16(vf, pb[mb][ks], o[mb][dt], 0, 0, 0);
        }
    }
    __syncthreads();   // protect Ks/Vs before next staging
  }

  // l-reduce across quads (lanes sharing l16) + write O^T as [row][h*64+d]
#pragma unroll
  for (int mb = 0; mb < 2; ++mb) {
    float l = lsum[mb];
    l += __shfl_xor(l, 16, 64);
    l += __shfl_xor(l, 32, 64);
    const float inv = 1.0f / l;
    const size_t row = (size_t)(b*SS + q0 + wave*32 + mb*16 + l16)*EMB + h*HDIM;
#pragma unroll
    for (int dt = 0; dt < 4; ++dt) {
      bf16x4_t v;
#pragma unroll
      for (int r = 0; r < 4; ++r) v[r] = (bf16_t)(o[mb][dt][r] * inv);
      *(bf16x4_t*)&Cx[row + dt*16 + quad*4] = v;
    }
  }
}

// ---------------------------------------------------------------------------
extern "C" void kernel_launch(void* const* d_in, const int* in_sizes, int n_in,
                              void* d_out, int out_size, void* d_ws, size_t ws_size,
                              hipStream_t stream) {
  (void)in_sizes; (void)n_in; (void)out_size;
  const float* query = (const float*)d_in[0];
  const float* key   = (const float*)d_in[1];
  const float* value = (const float*)d_in[2];
  const float* WqF   = (const float*)d_in[3];
  const float* WkF   = (const float*)d_in[4];
  const float* WvF   = (const float*)d_in[5];
  const float* WoF   = (const float*)d_in[6];

  const size_t AN = (size_t)MROWS*EMB;   // 8M elems
  const size_t WN = (size_t)EMB*EMB;     // 1M elems
  float* out = (float*)d_out;
  bf16_t* S5 = (bf16_t*)d_out;           // d_out first 16MB as bf16 scratch
  bf16_t* S6 = S5 + AN;                  // d_out second 16MB

  const float sscale = 0.125f * 1.44269504f;  // 1/sqrt(64)*log2(e) into Q

  const dim3 gqkv(EMB/128, MROWS/128, 3);
  const dim3 gqk (EMB/128, MROWS/128, 2);
  const dim3 gv  (EMB/128, MROWS/128, 1);
  const dim3 gg  (EMB/128, MROWS/128);
  const dim3 gattn(SS/128, HEADS, BB);

  if (ws_size >= (size_t)(4*AN + 4*WN) * sizeof(bf16_t)) {
    // ---- full-fusion path (ws >= 72MB): qb|kb|vb|S2|W in ws -------------
    bf16_t* qb  = (bf16_t*)d_ws;
    bf16_t* kb  = qb + AN;
    bf16_t* vb  = kb + AN;
    bf16_t* S2  = vb + AN;
    bf16_t* Wqb = S2 + AN;
    bf16_t* Wkb = Wqb + WN;
    bf16_t* Wvb = Wkb + WN;
    bf16_t* Wob = Wvb + WN;

    cast_multi<<<dim3(AN/2048, 1, 7), 256, 0, stream>>>(
        query, key, value, WqF, WkF, WvF, WoF,
        qb, kb, vb, Wqb, Wkb, Wvb, Wob, 3);
    gemm_qkv<<<gqkv, 256, 0, stream>>>(qb, kb, vb, Wqb, Wkb, Wvb,
                                       S2, S6, S5, sscale, 0);
    attn<<<gattn, 256, 0, stream>>>(S2, S6, S5, S2);
    gemm_out<<<gg, 256, 0, stream>>>(S2, Wob, out);
  } else {
    // ---- fallback path (ws >= 40MB proven): S1|S2|W in ws ---------------
    bf16_t* S1  = (bf16_t*)d_ws;
    bf16_t* S2  = S1 + AN;
    bf16_t* Wqb = S2 + AN;
    bf16_t* Wkb = Wqb + WN;
    bf16_t* Wvb = Wkb + WN;
    bf16_t* Wob = Wvb + WN;

    // z0: query->S1 (ws), z1: key->S5 (d_out), z2..5: weights
    cast_multi<<<dim3(AN/2048, 1, 6), 256, 0, stream>>>(
        query, key, WqF, WkF, WvF, WoF, WoF,
        S1, S5, Wqb, Wkb, Wvb, Wob, Wob, 2);
    gemm_qkv<<<gqk, 256, 0, stream>>>(S1, S5, S1, Wqb, Wkb, Wvb,
                                      S2, S6, S5, sscale, 0);   // Qp=S2, Kp=S6
    cast_f32_bf16<<<dim3(AN/2048), 256, 0, stream>>>(value, S1); // vb=S1 (qb dead)
    gemm_qkv<<<gv, 256, 0, stream>>>(S1, S1, S1, Wvb, Wvb, Wvb,
                                     S5, S5, S5, 1.0f, 2);      // Vt=S5 (kb dead)
    attn<<<gattn, 256, 0, stream>>>(S2, S6, S5, S2);            // Cx=S2
    gemm_out<<<gg, 256, 0, stream>>>(S2, Wob, out);
  }
}

// Round 7
// 323.848 us; speedup vs baseline: 2.0395x; 1.1274x over previous
//
#include <hip/hip_runtime.h>
#include <hip/hip_bf16.h>

#define EMB   1024
#define HEADS 16
#define HDIM  64
#define BB    4
#define SS    2048
#define MROWS (BB*SS)   // 8192

typedef __bf16 bf16_t;
typedef __bf16 bf16x4_t __attribute__((ext_vector_type(4)));
typedef __bf16 bf16x8   __attribute__((ext_vector_type(8)));
typedef float  f32x4    __attribute__((ext_vector_type(4)));

// async global->LDS, 16B/lane; LDS base wave-uniform, HW adds lane*16
__device__ __forceinline__ void glds16(const void* g, void* l) {
  __builtin_amdgcn_global_load_lds(
      (const __attribute__((address_space(1))) void*)g,
      (__attribute__((address_space(3))) void*)l, 16, 0, 0);
}

// ---------------------------------------------------------------------------
// Multi-tensor fp32->bf16 cast. z < nact: 8M-elem activations (4096 blocks);
// z >= nact: 1M-elem weights (first 512 blocks active).
// ---------------------------------------------------------------------------
__launch_bounds__(256)
__global__ void cast_multi(const float* s0, const float* s1, const float* s2,
                           const float* s3, const float* s4, const float* s5,
                           const float* s6,
                           bf16_t* d0, bf16_t* d1, bf16_t* d2, bf16_t* d3,
                           bf16_t* d4, bf16_t* d5, bf16_t* d6, int nact) {
  const int z = blockIdx.z;
  if (z >= nact && blockIdx.x >= 512) return;
  const float* ss[7] = {s0, s1, s2, s3, s4, s5, s6};
  bf16_t*      dd[7] = {d0, d1, d2, d3, d4, d5, d6};
  const float* s = ss[z];
  bf16_t*      d = dd[z];
  const int i = (blockIdx.x*256 + threadIdx.x) * 8;
  const f32x4 a = *(const f32x4*)&s[i];
  const f32x4 b = *(const f32x4*)&s[i+4];
  bf16x8 r;
  r[0]=(bf16_t)a[0]; r[1]=(bf16_t)a[1]; r[2]=(bf16_t)a[2]; r[3]=(bf16_t)a[3];
  r[4]=(bf16_t)b[0]; r[5]=(bf16_t)b[1]; r[6]=(bf16_t)b[2]; r[7]=(bf16_t)b[3];
  *(bf16x8*)&d[i] = r;
}

__launch_bounds__(256)
__global__ void cast_f32_bf16(const float* __restrict__ src, bf16_t* __restrict__ dst) {
  const int i = (blockIdx.x*256 + threadIdx.x) * 8;
  const f32x4 a = *(const f32x4*)&src[i];
  const f32x4 b = *(const f32x4*)&src[i+4];
  bf16x8 r;
  r[0]=(bf16_t)a[0]; r[1]=(bf16_t)a[1]; r[2]=(bf16_t)a[2]; r[3]=(bf16_t)a[3];
  r[4]=(bf16_t)b[0]; r[5]=(bf16_t)b[1]; r[6]=(bf16_t)b[2]; r[7]=(bf16_t)b[3];
  *(bf16x8*)&dst[i] = r;
}

// ---------------------------------------------------------------------------
// Shared GEMM core: acc[4][4] += A_tile @ W_tile^T over full K=EMB.
// 128x128 tile, BK=32, glds16 staging, 16 MFMA/K-step (m97 structure).
// ---------------------------------------------------------------------------
__device__ __forceinline__ void gemm_core(const bf16_t* __restrict__ A,
                                          const bf16_t* __restrict__ W,
                                          bf16_t* As, bf16_t* Bs,
                                          f32x4 acc[4][4],
                                          int bm0, int bn0,
                                          int wave, int lane) {
  const int quad = lane >> 4, l16 = lane & 15;
  const int wm = wave >> 1, wn = wave & 1;
  for (int k0 = 0; k0 < EMB; k0 += 32) {
#pragma unroll
    for (int j = 0; j < 2; ++j) {
      const int i   = wave*2 + j;              // chunk 0..7 (512 bf16 = 1KB)
      const int row = i*16 + (lane >> 2);
      const int col = (lane & 3) * 8;
      glds16(A + (size_t)(bm0 + row)*EMB + k0 + col, &As[i*512]);
      glds16(W + (size_t)(bn0 + row)*EMB + k0 + col, &Bs[i*512]);
    }
    __syncthreads();

    bf16x8 a[4], b[4];
#pragma unroll
    for (int t = 0; t < 4; ++t) {
      a[t] = *(const bf16x8*)&As[(wm*64 + t*16 + l16)*32 + quad*8];
      b[t] = *(const bf16x8*)&Bs[(wn*64 + t*16 + l16)*32 + quad*8];
    }
#pragma unroll
    for (int mt = 0; mt < 4; ++mt)
#pragma unroll
      for (int nt = 0; nt < 4; ++nt)
        acc[mt][nt] = __builtin_amdgcn_mfma_f32_16x16x32_bf16(a[mt], b[nt], acc[mt][nt], 0, 0, 0);
    __syncthreads();
  }
}

// ---------------------------------------------------------------------------
// Fused projection GEMM with XCD-aware swizzle.  Flat block id fid is
// round-robined over 8 XCDs by HW; we remap so each (z,bm) A-panel is owned
// by exactly one XCD (read once from HBM) with bn iterating time-locally,
// and W(z) (2MB) staying hot in that XCD's 4MB L2.
//   z (+zbase): 0 = Q (row-major, sscale), 1 = K (row-major), 2 = V (packed).
// ---------------------------------------------------------------------------
__launch_bounds__(256)
__global__ void gemm_qkv(const bf16_t* A0, const bf16_t* A1, const bf16_t* A2,
                         const bf16_t* W0, const bf16_t* W1, const bf16_t* W2,
                         bf16_t* C0, bf16_t* C1, bf16_t* C2,
                         float sscale, int zbase) {
  __shared__ __align__(16) bf16_t As[128*32];
  __shared__ __align__(16) bf16_t Bs[128*32];
  const int tid  = threadIdx.x;
  const int wave = tid >> 6, lane = tid & 63;
  const int quad = lane >> 4, l16 = lane & 15;
  const int wm = wave >> 1, wn = wave & 1;

  // XCD swizzle: fid -> (z, bm, bn)
  const int fid = blockIdx.x + 8*(blockIdx.y + 64*blockIdx.z);
  const int xcd = fid & 7, s = fid >> 3;
  const int bn0 = (s & 7) * 128;
  const int p   = xcd + 8*(s >> 3);            // (z,bm) pair, unique per XCD
  const int z   = (p >> 6) + zbase;
  const int bm0 = (p & 63) * 128;

  const bf16_t* A = (z == 0) ? A0 : (z == 1) ? A1 : A2;
  const bf16_t* W = (z == 0) ? W0 : (z == 1) ? W1 : W2;
  bf16_t*       C = (z == 0) ? C0 : (z == 1) ? C1 : C2;
  const float oscale = (z == 0) ? sscale : 1.0f;

  f32x4 acc[4][4] = {};
  gemm_core(A, W, As, Bs, acc, bm0, bn0, wave, lane);

  if (z == 2) {
    // packed-V^T epilogue: acc[mt][nt][r] = V[s=bm0+wm*64+mt*16+quad*4+r][d]
    // chunk(ks,nt) = {acc[2ks][nt][0..3], acc[2ks+1][nt][0..3]}
    const int bb = bm0 >> 11;                    // batch (2048 rows each)
    const int T  = ((bm0 & 2047) >> 6) + wm;     // 64-key tile within batch
    const int h  = (bn0 >> 6) + wn;              // head (64 cols each)
    bf16_t* base = C + ((size_t)(bb*HEADS + h)*32 + T)*4096;
#pragma unroll
    for (int ks = 0; ks < 2; ++ks)
#pragma unroll
      for (int nt = 0; nt < 4; ++nt) {
        bf16x8 v;
#pragma unroll
        for (int r = 0; r < 4; ++r) {
          v[r]     = (bf16_t)acc[2*ks][nt][r];
          v[4 + r] = (bf16_t)acc[2*ks + 1][nt][r];
        }
        *(bf16x8*)&base[((nt*2 + ks)*64 + quad*16 + l16)*8] = v;
      }
  } else {
    // row-major epilogue: C/D layout col=l16, row=quad*4+reg
#pragma unroll
    for (int mt = 0; mt < 4; ++mt) {
      const int row = bm0 + wm*64 + mt*16 + quad*4;
#pragma unroll
      for (int nt = 0; nt < 4; ++nt) {
        const int col = bn0 + wn*64 + nt*16 + l16;
#pragma unroll
        for (int r = 0; r < 4; ++r)
          C[(size_t)(row + r)*EMB + col] = (bf16_t)(acc[mt][nt][r] * oscale);
      }
    }
  }
}

// output GEMM: fp32 C, row-major, XCD swizzle (8 bm-panels per XCD, W hot)
__launch_bounds__(256)
__global__ void gemm_out(const bf16_t* __restrict__ A, const bf16_t* __restrict__ W,
                         float* __restrict__ C) {
  __shared__ __align__(16) bf16_t As[128*32];
  __shared__ __align__(16) bf16_t Bs[128*32];
  const int tid  = threadIdx.x;
  const int wave = tid >> 6, lane = tid & 63;
  const int quad = lane >> 4, l16 = lane & 15;
  const int wm = wave >> 1, wn = wave & 1;

  const int fid = blockIdx.x + 8*blockIdx.y;
  const int xcd = fid & 7, s = fid >> 3;
  const int bn0 = (s & 7) * 128;
  const int bm0 = (xcd*8 + (s >> 3)) * 128;

  f32x4 acc[4][4] = {};
  gemm_core(A, W, As, Bs, acc, bm0, bn0, wave, lane);

#pragma unroll
  for (int mt = 0; mt < 4; ++mt) {
    const int row = bm0 + wm*64 + mt*16 + quad*4;
#pragma unroll
    for (int nt = 0; nt < 4; ++nt) {
      const int col = bn0 + wn*64 + nt*16 + l16;
#pragma unroll
      for (int r = 0; r < 4; ++r)
        C[(size_t)(row + r)*EMB + col] = acc[mt][nt][r];
    }
  }
}

// ---------------------------------------------------------------------------
// Flash attention, Q-tile 128 (4 waves x 32 rows), K-tile 64, no P LDS
// round-trip:  S^T = MFMA(A=K, B=Q) gives the P^T B-operand layout directly
// (regs = 4 keys, lane = qrow); packed V^T from the V-GEMM epilogue is the
// A-operand of O^T = V^T P^T with zero data movement.  No-max softmax (scale
// folded into Q projection), raw v_exp_f32, deferred l-reduction.
// XCD swizzle: all 16 q-blocks of one (b,h) land consecutively on one XCD,
// so that pair's K/V (0.5MB) is fetched from HBM once and served from L2.
// Qp and Cx alias (disjoint per-block slices, read-before-write).
// ---------------------------------------------------------------------------
__launch_bounds__(256)
__global__ void attn(const bf16_t* Qp, const bf16_t* __restrict__ Kp,
                     const bf16_t* __restrict__ Vt, bf16_t* Cx) {
  __shared__ __align__(16) bf16_t Ks[2*64*32];  // [d-half][key][32]   8KB
  __shared__ __align__(16) bf16_t Vs[4096];     // packed V^T chunks   8KB

  const int tid  = threadIdx.x;
  const int wave = tid >> 6, lane = tid & 63;
  const int quad = lane >> 4, l16 = lane & 15;

  // XCD swizzle: fid -> (b, h, q-block); gridDim = (16, 16, 4)
  const int fid  = blockIdx.x + 16*(blockIdx.y + 16*blockIdx.z);
  const int xcd  = fid & 7, s = fid >> 3;
  const int q0   = (s & 15) * 128;
  const int pair = xcd*8 + (s >> 4);    // 0..63, unique per XCD
  const int h    = pair & 15;
  const int b    = pair >> 4;

  // Q fragments (B-operand of S^T): lane l16 = qrow, k = d = quad*8+j (+32ks)
  bf16x8 qf[2][2];
#pragma unroll
  for (int mb = 0; mb < 2; ++mb) {
    const size_t qr = (size_t)(b*SS + q0 + wave*32 + mb*16 + l16)*EMB + h*HDIM;
#pragma unroll
    for (int ks = 0; ks < 2; ++ks)
      qf[mb][ks] = *(const bf16x8*)&Qp[qr + ks*32 + quad*8];
  }

  const bf16_t* Kb = Kp + (size_t)b*SS*EMB + h*HDIM;
  const bf16_t* Vb = Vt + ((size_t)(b*HEADS + h)*32)*4096;

  f32x4 o[2][4] = {};          // O^T: lane l16 = qrow, row = d = quad*4+r
  float lsum[2] = {0.f, 0.f};

  for (int t0 = 0; t0 < SS; t0 += 64) {
    // stage K (row-major halves) + packed V^T (identity copy): 4 glds16/wave
#pragma unroll
    for (int c = 0; c < 2; ++c) {
      const int i   = wave + c*4;
      const int r   = (i & 3)*16 + (lane >> 2);
      const int col = (lane & 3)*8;
      glds16(Kb + (size_t)(t0 + r)*EMB + c*32 + col, &Ks[i*512]);
      glds16(Vb + (size_t)(t0 >> 6)*4096 + i*512 + lane*8, &Vs[i*512]);
    }
    __syncthreads();

    // S^T = K Q^T : A = K-frag (lane l16 = key), B = Q-frag  (16 MFMA)
    f32x4 st[2][4] = {};
#pragma unroll
    for (int cb = 0; cb < 4; ++cb) {
      const bf16x8 kf0 = *(const bf16x8*)&Ks[(cb*16 + l16)*32 + quad*8];
      const bf16x8 kf1 = *(const bf16x8*)&Ks[2048 + (cb*16 + l16)*32 + quad*8];
#pragma unroll
      for (int mb = 0; mb < 2; ++mb) {
        st[mb][cb] = __builtin_amdgcn_mfma_f32_16x16x32_bf16(kf0, qf[mb][0], st[mb][cb], 0, 0, 0);
        st[mb][cb] = __builtin_amdgcn_mfma_f32_16x16x32_bf16(kf1, qf[mb][1], st[mb][cb], 0, 0, 0);
      }
    }

    // softmax (no-max): p = exp2(s); pack P^T B-fragments directly from regs
    bf16x8 pb[2][2];
#pragma unroll
    for (int mb = 0; mb < 2; ++mb) {
      float ls = 0.f;
#pragma unroll
      for (int kb = 0; kb < 4; ++kb)
#pragma unroll
        for (int r = 0; r < 4; ++r) {
          const float p = __builtin_amdgcn_exp2f(st[mb][kb][r]);
          st[mb][kb][r] = p;
          ls += p;
        }
      lsum[mb] += ls;
#pragma unroll
      for (int ks = 0; ks < 2; ++ks)
#pragma unroll
        for (int r = 0; r < 4; ++r) {
          pb[mb][ks][r]     = (bf16_t)st[mb][2*ks][r];
          pb[mb][ks][4 + r] = (bf16_t)st[mb][2*ks + 1][r];
        }
    }

    // O^T += V^T P^T : A = packed V^T chunk, B = pb  (16 MFMA)
#pragma unroll
    for (int ks = 0; ks < 2; ++ks)
#pragma unroll
      for (int dt = 0; dt < 4; ++dt) {
        const bf16x8 vf = *(const bf16x8*)&Vs[((dt*2 + ks)*64 + quad*16 + l16)*8];
#pragma unroll
        for (int mb = 0; mb < 2; ++mb)
          o[mb][dt] = __builtin_amdgcn_mfma_f32_16x16x32_bf16(vf, pb[mb][ks], o[mb][dt], 0, 0, 0);
      }
    __syncthreads();   // protect Ks/Vs before next staging
  }

  // l-reduce across quads (lanes sharing l16) + write O^T as [row][h*64+d]
#pragma unroll
  for (int mb = 0; mb < 2; ++mb) {
    float l = lsum[mb];
    l += __shfl_xor(l, 16, 64);
    l += __shfl_xor(l, 32, 64);
    const float inv = 1.0f / l;
    const size_t row = (size_t)(b*SS + q0 + wave*32 + mb*16 + l16)*EMB + h*HDIM;
#pragma unroll
    for (int dt = 0; dt < 4; ++dt) {
      bf16x4_t v;
#pragma unroll
      for (int r = 0; r < 4; ++r) v[r] = (bf16_t)(o[mb][dt][r] * inv);
      *(bf16x4_t*)&Cx[row + dt*16 + quad*4] = v;
    }
  }
}

// ---------------------------------------------------------------------------
extern "C" void kernel_launch(void* const* d_in, const int* in_sizes, int n_in,
                              void* d_out, int out_size, void* d_ws, size_t ws_size,
                              hipStream_t stream) {
  (void)in_sizes; (void)n_in; (void)out_size;
  const float* query = (const float*)d_in[0];
  const float* key   = (const float*)d_in[1];
  const float* value = (const float*)d_in[2];
  const float* WqF   = (const float*)d_in[3];
  const float* WkF   = (const float*)d_in[4];
  const float* WvF   = (const float*)d_in[5];
  const float* WoF   = (const float*)d_in[6];

  const size_t AN = (size_t)MROWS*EMB;   // 8M elems
  const size_t WN = (size_t)EMB*EMB;     // 1M elems
  float* out = (float*)d_out;
  bf16_t* S5 = (bf16_t*)d_out;           // d_out first 16MB as bf16 scratch
  bf16_t* S6 = S5 + AN;                  // d_out second 16MB

  const float sscale = 0.125f * 1.44269504f;  // 1/sqrt(64)*log2(e) into Q

  const dim3 gqkv(EMB/128, MROWS/128, 3);
  const dim3 gqk (EMB/128, MROWS/128, 2);
  const dim3 gv  (EMB/128, MROWS/128, 1);
  const dim3 gg  (EMB/128, MROWS/128);
  const dim3 gattn(SS/128, HEADS, BB);

  if (ws_size >= (size_t)(4*AN + 4*WN) * sizeof(bf16_t)) {
    // ---- full-fusion path (ws >= 72MB): qb|kb|vb|S2|W in ws -------------
    bf16_t* qb  = (bf16_t*)d_ws;
    bf16_t* kb  = qb + AN;
    bf16_t* vb  = kb + AN;
    bf16_t* S2  = vb + AN;
    bf16_t* Wqb = S2 + AN;
    bf16_t* Wkb = Wqb + WN;
    bf16_t* Wvb = Wkb + WN;
    bf16_t* Wob = Wvb + WN;

    cast_multi<<<dim3(AN/2048, 1, 7), 256, 0, stream>>>(
        query, key, value, WqF, WkF, WvF, WoF,
        qb, kb, vb, Wqb, Wkb, Wvb, Wob, 3);
    gemm_qkv<<<gqkv, 256, 0, stream>>>(qb, kb, vb, Wqb, Wkb, Wvb,
                                       S2, S6, S5, sscale, 0);
    attn<<<gattn, 256, 0, stream>>>(S2, S6, S5, S2);
    gemm_out<<<gg, 256, 0, stream>>>(S2, Wob, out);
  } else {
    // ---- fallback path (ws >= 40MB proven): S1|S2|W in ws ---------------
    bf16_t* S1  = (bf16_t*)d_ws;
    bf16_t* S2  = S1 + AN;
    bf16_t* Wqb = S2 + AN;
    bf16_t* Wkb = Wqb + WN;
    bf16_t* Wvb = Wkb + WN;
    bf16_t* Wob = Wvb + WN;

    // z0: query->S1 (ws), z1: key->S5 (d_out), z2..5: weights
    cast_multi<<<dim3(AN/2048, 1, 6), 256, 0, stream>>>(
        query, key, WqF, WkF, WvF, WoF, WoF,
        S1, S5, Wqb, Wkb, Wvb, Wob, Wob, 2);
    gemm_qkv<<<gqk, 256, 0, stream>>>(S1, S5, S1, Wqb, Wkb, Wvb,
                                      S2, S6, S5, sscale, 0);   // Qp=S2, Kp=S6
    cast_f32_bf16<<<dim3(AN/2048), 256, 0, stream>>>(value, S1); // vb=S1 (qb dead)
    gemm_qkv<<<gv, 256, 0, stream>>>(S1, S1, S1, Wvb, Wvb, Wvb,
                                     S5, S5, S5, 1.0f, 2);      // Vt=S5 (kb dead)
    attn<<<gattn, 256, 0, stream>>>(S2, S6, S5, S2);            // Cx=S2
    gemm_out<<<gg, 256, 0, stream>>>(S2, Wob, out);
  }
}